// Round 3
// baseline (340.442 us; speedup 1.0000x reference)
//
#include <hip/hip_runtime.h>
#include <hip/hip_bf16.h>
#include <cstdint>

// VQ quantizer: dist argmin over 8192 codes, gather, loss.
// R3: deep-pipelined main GEMM — BM512xBN128xBK32, K_eff=768 (hi/lo 3-pass as
// virtual-K), 3-buffer LDS rotation, counted vmcnt(5), setprio MFMA clusters,
// T2 chunk-XOR swizzle (both-sides), XCD-aware block swizzle.

typedef __bf16 bf16x8 __attribute__((ext_vector_type(8)));
typedef __bf16 bf16x4 __attribute__((ext_vector_type(4)));
typedef float  f32x4  __attribute__((ext_vector_type(4)));

#define N_ROWS  16384
#define N_CODES 8192
#define DDIM    256

#define BUFB    40960          // 32KB A + 8KB B per K-tile buffer
#define NT      24             // 768 / 32 virtual K-tiles

#define STAGE16(gptr, lptr) __builtin_amdgcn_global_load_lds( \
    (const __attribute__((address_space(1))) void*)(gptr),    \
    (__attribute__((address_space(3))) void*)(lptr), 16, 0, 0)

#define SBAR() do { asm volatile("" ::: "memory"); \
                    __builtin_amdgcn_s_barrier();  \
                    asm volatile("" ::: "memory"); } while (0)
#define WAITVM(N) asm volatile("s_waitcnt vmcnt(" #N ")" ::: "memory")

// ---------- prep: split x (f32) into bf16 hi/lo planes ----------
__global__ void prep_x_k(const float* __restrict__ x,
                         __bf16* __restrict__ xhi, __bf16* __restrict__ xlo) {
  int i = blockIdx.x * 256 + threadIdx.x;
  float4 v = reinterpret_cast<const float4*>(x)[i];
  float a[4] = {v.x, v.y, v.z, v.w};
  bf16x4 h, l;
#pragma unroll
  for (int j = 0; j < 4; ++j) {
    __bf16 hh = (__bf16)a[j];
    h[j] = hh;
    l[j] = (__bf16)(a[j] - (float)hh);
  }
  reinterpret_cast<bf16x4*>(xhi)[i] = h;
  reinterpret_cast<bf16x4*>(xlo)[i] = l;
}

// ---------- prep: transpose emb [256][8192] -> [8192][256]; split + f32 copy ----------
__global__ void prep_e_k(const float* __restrict__ emb,
                         __bf16* __restrict__ ehi, __bf16* __restrict__ elo,
                         float* __restrict__ embT) {
  __shared__ float tile[64][65];
  const int kb = blockIdx.x * 64, db = blockIdx.y * 64;
  const int t = threadIdx.x;
  const int tk = t & 63, td = t >> 6;
#pragma unroll
  for (int c = 0; c < 16; ++c) {
    int d = c * 4 + td;
    tile[d][tk] = emb[(size_t)(db + d) * N_CODES + kb + tk];
  }
  __syncthreads();
#pragma unroll
  for (int c = 0; c < 16; ++c) {
    int k = c * 4 + td;
    int d = tk;
    float v = tile[d][k];
    size_t o = (size_t)(kb + k) * DDIM + db + d;
    __bf16 h = (__bf16)v;
    embT[o] = v;
    ehi[o] = h;
    elo[o] = (__bf16)(v - (float)h);
  }
}

// ---------- prep: ||e_k||^2 in exact f32 ----------
__global__ void enorm_k(const float* __restrict__ emb, float* __restrict__ enorm) {
  int k = blockIdx.x * 256 + threadIdx.x;
  float s = 0.f;
  for (int d = 0; d < DDIM; ++d) {
    float v = emb[(size_t)d * N_CODES + k];
    s += v * v;
  }
  enorm[k] = s;
}

// ---------- main: 512x128 tile, virtual-K 768, 3-buf pipeline + argmin ----------
// Swizzle: LDS row = 64B = 4x16B chunks; data (row, c) lives at phys chunk
// c ^ ((row>>1)&3). gload_lds writes linearly -> global SOURCE pre-swizzled;
// ds_read applies the same XOR. 2 lanes/bank on fragment reads (free).
#define MROW(M, AV) \
  acc[M][0] = __builtin_amdgcn_mfma_f32_16x16x32_bf16(AV, b0, acc[M][0], 0, 0, 0); \
  acc[M][1] = __builtin_amdgcn_mfma_f32_16x16x32_bf16(AV, b1, acc[M][1], 0, 0, 0); \
  acc[M][2] = __builtin_amdgcn_mfma_f32_16x16x32_bf16(AV, b2, acc[M][2], 0, 0, 0); \
  acc[M][3] = __builtin_amdgcn_mfma_f32_16x16x32_bf16(AV, b3, acc[M][3], 0, 0, 0);

#define PLANE_A(s) ((((s) >> 3) == 1) ? (const char*)xlo : (const char*)xhi)
#define PLANE_B(s) ((((s) >> 3) == 2) ? (const char*)elo : (const char*)ehi)
#define COLB(s) (((s) & 7) << 6)

__global__ __launch_bounds__(512, 2) void vq_main_k(
    const __bf16* __restrict__ xhi, const __bf16* __restrict__ xlo,
    const __bf16* __restrict__ ehi, const __bf16* __restrict__ elo,
    const float* __restrict__ enorm, unsigned long long* __restrict__ keys) {
  extern __shared__ __align__(16) unsigned char smem[];

  const int tid = threadIdx.x;
  const int wid = tid >> 6, lane = tid & 63;
  const int wr = wid >> 1, wc = wid & 1;      // 4M x 2N waves, 128x64 each

  int wg = blockIdx.x;
  wg = (wg & 7) * 256 + (wg >> 3);            // XCD swizzle (2048 % 8 == 0)
  const int bm = wg & 31, bn = wg >> 5;       // 32 x 64 tiles

  // staging: per gload instr, lane l covers (row = l>>2, phys chunk = l&3);
  // fetch global logical chunk (l&3)^((l>>3)&3)  [inverse of read swizzle]
  const int stageLaneOff = (lane >> 2) * 512 + (((lane & 3) ^ ((lane >> 3) & 3)) << 4);
  const size_t Asb = (size_t)bm * 512 * 512 + (size_t)wid * 32768;  // bytes
  const size_t Bsb = (size_t)bn * 128 * 512 + (size_t)wid * 8192;
  const int ldsAu = wid * 4096;               // wave's 4 A-units (1KB each)
  const int ldsBu = 32768 + wid * 1024;       // wave's 1 B-unit

  // fragment-read offsets (bytes)
  const int rrow = lane & 15;
  const int cph  = (((lane >> 4) ^ ((rrow >> 1) & 3)) << 4);
  const int rdA  = (wr * 128 + rrow) * 64 + cph;
  const int rdB  = 32768 + (wc * 64 + rrow) * 64 + cph;

  f32x4 acc[8][4] = {};

  // prologue: stage tiles 0 -> buf0, 1 -> buf1 (5 loads each per wave)
  {
    const char* Ap = PLANE_A(0) + Asb + COLB(0) + stageLaneOff;
    const char* Bp = PLANE_B(0) + Bsb + COLB(0) + stageLaneOff;
    STAGE16(Ap,         smem + ldsAu);
    STAGE16(Ap +  8192, smem + ldsAu + 1024);
    STAGE16(Ap + 16384, smem + ldsAu + 2048);
    STAGE16(Ap + 24576, smem + ldsAu + 3072);
    STAGE16(Bp,         smem + ldsBu);
    const char* Ap1 = PLANE_A(1) + Asb + COLB(1) + stageLaneOff;
    const char* Bp1 = PLANE_B(1) + Bsb + COLB(1) + stageLaneOff;
    STAGE16(Ap1,         smem + BUFB + ldsAu);
    STAGE16(Ap1 +  8192, smem + BUFB + ldsAu + 1024);
    STAGE16(Ap1 + 16384, smem + BUFB + ldsAu + 2048);
    STAGE16(Ap1 + 24576, smem + BUFB + ldsAu + 3072);
    STAGE16(Bp1,         smem + BUFB + ldsBu);
  }
  WAITVM(5);   // tile 0 landed; tile 1 still in flight
  SBAR();

  int bo0 = 0, bo1 = BUFB, bo2 = 2 * BUFB;
#pragma unroll 1
  for (int t = 0; t < NT; ++t) {
    int s = t + 2; if (s >= NT) s -= NT;      // wrap keeps vmcnt count uniform
    const char* Ap = PLANE_A(s) + Asb + COLB(s) + stageLaneOff;
    const char* Bp = PLANE_B(s) + Bsb + COLB(s) + stageLaneOff;
    unsigned char* stA = smem + bo2 + ldsAu;
    const unsigned char* rb = smem + bo0;

    // ---- phase 0: read B + A(m0-3), issue 3 stage loads, 16 MFMA ----
    bf16x8 b0 = *(const bf16x8*)(rb + rdB);
    bf16x8 b1 = *(const bf16x8*)(rb + rdB + 1024);
    bf16x8 b2 = *(const bf16x8*)(rb + rdB + 2048);
    bf16x8 b3 = *(const bf16x8*)(rb + rdB + 3072);
    bf16x8 a0 = *(const bf16x8*)(rb + rdA);
    bf16x8 a1 = *(const bf16x8*)(rb + rdA + 1024);
    bf16x8 a2 = *(const bf16x8*)(rb + rdA + 2048);
    bf16x8 a3 = *(const bf16x8*)(rb + rdA + 3072);
    STAGE16(Ap,         stA);
    STAGE16(Ap +  8192, stA + 1024);
    STAGE16(Ap + 16384, stA + 2048);
    SBAR();
    __builtin_amdgcn_s_setprio(1);
    MROW(0, a0) MROW(1, a1) MROW(2, a2) MROW(3, a3)
    __builtin_amdgcn_s_setprio(0);

    // ---- phase 1: read A(m4-7), issue 2 stage loads, 16 MFMA ----
    bf16x8 a4 = *(const bf16x8*)(rb + rdA + 4096);
    bf16x8 a5 = *(const bf16x8*)(rb + rdA + 5120);
    bf16x8 a6 = *(const bf16x8*)(rb + rdA + 6144);
    bf16x8 a7 = *(const bf16x8*)(rb + rdA + 7168);
    STAGE16(Ap + 24576, stA + 3072);
    STAGE16(Bp,         smem + bo2 + ldsBu);
    SBAR();
    __builtin_amdgcn_s_setprio(1);
    MROW(4, a4) MROW(5, a5) MROW(6, a6) MROW(7, a7)
    __builtin_amdgcn_s_setprio(0);

    WAITVM(5);                                 // drain tile t+1 (keep t+2 in flight)
    SBAR();
    int bt = bo0; bo0 = bo1; bo1 = bo2; bo2 = bt;
  }
  WAITVM(0);

  // epilogue: score = ||e||^2 - 2*dot ; per-row argmin -> 64-bit key atomicMin
  const int codeBase = bn * 128 + wc * 64 + rrow;
  float en[4];
#pragma unroll
  for (int n = 0; n < 4; ++n) en[n] = enorm[codeBase + n * 16];
  const int rowBase = bm * 512 + wr * 128 + ((lane >> 4) << 2);
#pragma unroll
  for (int m = 0; m < 8; ++m) {
#pragma unroll
    for (int r = 0; r < 4; ++r) {
      unsigned long long best = ~0ull;
#pragma unroll
      for (int n = 0; n < 4; ++n) {
        float sc = en[n] - 2.0f * acc[m][n][r];
        unsigned u = __float_as_uint(sc);
        u = (u & 0x80000000u) ? ~u : (u | 0x80000000u);
        unsigned long long key = ((unsigned long long)u << 32) | (unsigned)(codeBase + n * 16);
        best = key < best ? key : best;
      }
#pragma unroll
      for (int mk = 1; mk <= 8; mk <<= 1) {
        unsigned lo32 = (unsigned)best, hi32 = (unsigned)(best >> 32);
        lo32 = __shfl_xor(lo32, mk, 64);
        hi32 = __shfl_xor(hi32, mk, 64);
        unsigned long long o = ((unsigned long long)hi32 << 32) | lo32;
        best = o < best ? o : best;
      }
      if (rrow == 0 && (lane >> 4) == ((lane >> 4)))  // lane&15 == 0 writes
        ;
      if ((lane & 15) == 0) atomicMin(&keys[rowBase + m * 16 + r], best);
    }
  }
}

// ---------- gather q (exact f32), q_st out, per-row squared error ----------
__global__ void gather_k(const float* __restrict__ x, const float* __restrict__ embT,
                         const unsigned long long* __restrict__ keys,
                         float* __restrict__ qout, float* __restrict__ rowsum) {
  const int row = blockIdx.x;
  const int lane = threadIdx.x;
  const int idx = (int)(keys[row] & 0xffffffffull);
  float4 q  = reinterpret_cast<const float4*>(embT + (size_t)idx * DDIM)[lane];
  float4 xv = reinterpret_cast<const float4*>(x + (size_t)row * DDIM)[lane];
  reinterpret_cast<float4*>(qout + (size_t)row * DDIM)[lane] = q;
  float dx = q.x - xv.x, dy = q.y - xv.y, dz = q.z - xv.z, dw = q.w - xv.w;
  float s = dx * dx + dy * dy + dz * dz + dw * dw;
#pragma unroll
  for (int mk = 32; mk; mk >>= 1) s += __shfl_xor(s, mk, 64);
  if (lane == 0) rowsum[row] = s;
}

// ---------- deterministic final loss reduce ----------
__global__ void loss_k(const float* __restrict__ rowsum, float* __restrict__ out) {
  __shared__ float sm[4];
  const int t = threadIdx.x;
  float s = 0.f;
  for (int j = t; j < N_ROWS; j += 256) s += rowsum[j];
#pragma unroll
  for (int mk = 32; mk; mk >>= 1) s += __shfl_xor(s, mk, 64);
  if ((t & 63) == 0) sm[t >> 6] = s;
  __syncthreads();
  if (t == 0) out[0] = 2.0f * (sm[0] + sm[1] + sm[2] + sm[3]) / (float)(N_ROWS * DDIM);
}

extern "C" void kernel_launch(void* const* d_in, const int* in_sizes, int n_in,
                              void* d_out, int out_size, void* d_ws, size_t ws_size,
                              hipStream_t stream) {
  const float* x   = (const float*)d_in[0];          // [16,1024,256] f32
  const float* emb = (const float*)d_in[1];          // [256,8192] f32
  float* qout = (float*)d_out;                       // 4,194,304 q_st + 1 loss

  char* w = (char*)d_ws;
  unsigned long long* keys = (unsigned long long*)w;                 // 128 KB
  float* rowsum = (float*)(w + 131072);                              // 64 KB
  __bf16* xhi = (__bf16*)(w + 196608);                               // 8 MB
  __bf16* xlo = xhi + (size_t)N_ROWS * DDIM;                         // 8 MB
  __bf16* ehi = xlo + (size_t)N_ROWS * DDIM;                         // 4 MB
  __bf16* elo = ehi + (size_t)N_CODES * DDIM;                        // 4 MB
  float*  embT = (float*)(elo + (size_t)N_CODES * DDIM);             // 8 MB
  float*  enorm = embT + (size_t)N_CODES * DDIM;                     // 32 KB

  hipFuncSetAttribute((const void*)vq_main_k,
                      hipFuncAttributeMaxDynamicSharedMemorySize, 3 * BUFB);

  hipMemsetAsync(keys, 0xFF, N_ROWS * sizeof(unsigned long long), stream);
  prep_x_k<<<4096, 256, 0, stream>>>(x, xhi, xlo);
  prep_e_k<<<dim3(N_CODES / 64, DDIM / 64), 256, 0, stream>>>(emb, ehi, elo, embT);
  enorm_k<<<N_CODES / 256, 256, 0, stream>>>(emb, enorm);
  vq_main_k<<<2048, 512, 3 * BUFB, stream>>>(xhi, xlo, ehi, elo, enorm, keys);
  gather_k<<<N_ROWS, 64, 0, stream>>>(x, embT, keys, qout, rowsum);
  loss_k<<<1, 256, 0, stream>>>(rowsum, qout + (size_t)N_ROWS * DDIM);
}

// Round 4
// 297.338 us; speedup vs baseline: 1.1450x; 1.1450x over previous
//
#include <hip/hip_runtime.h>
#include <hip/hip_bf16.h>
#include <cstdint>

// VQ quantizer: dist argmin over 8192 codes, gather, loss.
// R4: R2's proven 128x128 / 4-wave / 3-pass hi/lo core + BK=32 double-buffer
// pipeline (stage-early, single barrier + vmcnt per tile, setprio MFMA) +
// L2-fitting XCD swizzle (16-bm window per XCD). T2 chunk-XOR swizzle kept.

typedef __bf16 bf16x8 __attribute__((ext_vector_type(8)));
typedef __bf16 bf16x4 __attribute__((ext_vector_type(4)));
typedef float  f32x4  __attribute__((ext_vector_type(4)));

#define N_ROWS  16384
#define N_CODES 8192
#define DDIM    256
#define NT      8              // 256 / BK32 K-tiles

#define STAGE16(gptr, lptr) __builtin_amdgcn_global_load_lds( \
    (const __attribute__((address_space(1))) void*)(gptr),    \
    (__attribute__((address_space(3))) void*)(lptr), 16, 0, 0)

#define SBAR() do { asm volatile("" ::: "memory"); \
                    __builtin_amdgcn_s_barrier();  \
                    asm volatile("" ::: "memory"); } while (0)
#define WAITVM0() asm volatile("s_waitcnt vmcnt(0)" ::: "memory")

// ---------- prep: split x (f32) into bf16 hi/lo planes ----------
__global__ void prep_x_k(const float* __restrict__ x,
                         __bf16* __restrict__ xhi, __bf16* __restrict__ xlo) {
  int i = blockIdx.x * 256 + threadIdx.x;
  float4 v = reinterpret_cast<const float4*>(x)[i];
  float a[4] = {v.x, v.y, v.z, v.w};
  bf16x4 h, l;
#pragma unroll
  for (int j = 0; j < 4; ++j) {
    __bf16 hh = (__bf16)a[j];
    h[j] = hh;
    l[j] = (__bf16)(a[j] - (float)hh);
  }
  reinterpret_cast<bf16x4*>(xhi)[i] = h;
  reinterpret_cast<bf16x4*>(xlo)[i] = l;
}

// ---------- prep: transpose emb [256][8192] -> [8192][256]; split + f32 copy ----------
__global__ void prep_e_k(const float* __restrict__ emb,
                         __bf16* __restrict__ ehi, __bf16* __restrict__ elo,
                         float* __restrict__ embT) {
  __shared__ float tile[64][65];
  const int kb = blockIdx.x * 64, db = blockIdx.y * 64;
  const int t = threadIdx.x;
  const int tk = t & 63, td = t >> 6;
#pragma unroll
  for (int c = 0; c < 16; ++c) {
    int d = c * 4 + td;
    tile[d][tk] = emb[(size_t)(db + d) * N_CODES + kb + tk];
  }
  __syncthreads();
#pragma unroll
  for (int c = 0; c < 16; ++c) {
    int k = c * 4 + td;
    int d = tk;
    float v = tile[d][k];
    size_t o = (size_t)(kb + k) * DDIM + db + d;
    __bf16 h = (__bf16)v;
    embT[o] = v;
    ehi[o] = h;
    elo[o] = (__bf16)(v - (float)h);
  }
}

// ---------- prep: ||e_k||^2 in exact f32 ----------
__global__ void enorm_k(const float* __restrict__ emb, float* __restrict__ enorm) {
  int k = blockIdx.x * 256 + threadIdx.x;
  float s = 0.f;
  for (int d = 0; d < DDIM; ++d) {
    float v = emb[(size_t)d * N_CODES + k];
    s += v * v;
  }
  enorm[k] = s;
}

// ---------- main: 128x128 tile, BK=32 dbuf pipeline, 3-pass hi/lo + argmin ----------
// LDS buffer (32KB): Ah[128][32] @0, Al @8K, Bh @16K, Bl @24K (rows = 64B).
// Swizzle: logical (row, chunk c) lives at phys chunk c ^ ((row>>1)&3);
// gload_lds dest linear -> global SOURCE pre-swizzled, reads apply same XOR.
__global__ __launch_bounds__(256, 2) void vq_main_k(
    const __bf16* __restrict__ xhi, const __bf16* __restrict__ xlo,
    const __bf16* __restrict__ ehi, const __bf16* __restrict__ elo,
    const float* __restrict__ enorm, unsigned long long* __restrict__ keys) {
  __shared__ alignas(16) unsigned char smem[2][32768];

  const int tid = threadIdx.x;
  const int wid = tid >> 6, lane = tid & 63;
  const int wr = wid >> 1, wc = wid & 1;       // 2x2 waves, 64x64 each

  // XCD swizzle: xcd = orig&7 owns logical ids [xcd*1024, +1024): a 16-bm
  // window (2MB of A, L2-resident) swept over all 64 bn panels.
  const int orig = blockIdx.x;
  const int l = (orig & 7) * 1024 + (orig >> 3);
  const int bm = ((l >> 10) << 4) + (l & 15);  // 0..127
  const int bn = (l >> 4) & 63;                // 0..63

  // staging geometry: wave w covers rows 32w..32w+31 of all 4 planes
  const int ur = wid * 32;
  const int lrow = lane >> 2;                                    // 0..15
  const int lchunk = ((lane & 3) ^ ((lane >> 3) & 3)) << 4;      // pre-swizzled
  const size_t aRow0 = (size_t)(bm * 128 + ur) * 512;            // bytes
  const size_t bRow0 = (size_t)(bn * 128 + ur) * 512;
  const size_t stSrc = (size_t)lrow * 512 + lchunk;

  // fragment-read offsets (bytes within a plane)
  const int rrow = lane & 15;
  const int cph = (((lane >> 4) ^ ((rrow >> 1) & 3)) << 4);
  const int rdA = (wr * 64 + rrow) * 64 + cph;   // + m*1024
  const int rdB = (wc * 64 + rrow) * 64 + cph;   // + n*1024

  const char* xh = (const char*)xhi; const char* xl = (const char*)xlo;
  const char* eh = (const char*)ehi; const char* el = (const char*)elo;
  unsigned char* s0 = &smem[0][0];

  // hoist enorm loads (land under the GEMM)
  const int codeBase = bn * 128 + wc * 64 + rrow;
  float en0 = enorm[codeBase], en1 = enorm[codeBase + 16];
  float en2 = enorm[codeBase + 32], en3 = enorm[codeBase + 48];

  f32x4 acc[4][4] = {};

  // prologue: tile 0 -> buf 0
#pragma unroll
  for (int u = 0; u < 2; ++u) {
    const size_t ga = aRow0 + (size_t)(u * 16) * 512 + stSrc;
    const size_t gb = bRow0 + (size_t)(u * 16) * 512 + stSrc;
    const int d = ur * 64 + u * 1024;
    STAGE16(xh + ga, s0 + d);
    STAGE16(xl + ga, s0 + 8192 + d);
    STAGE16(eh + gb, s0 + 16384 + d);
    STAGE16(el + gb, s0 + 24576 + d);
  }
  WAITVM0();
  SBAR();

  int cur = 0;
#pragma unroll 1
  for (int t = 0; t < NT; ++t) {
    const unsigned char* rb = s0 + cur * 32768;
    unsigned char* wb = s0 + (cur ^ 1) * 32768;

    // issue next tile's stage first (lands under this tile's MFMA)
    if (t < NT - 1) {
      const size_t koff = (size_t)((t + 1) << 6);
#pragma unroll
      for (int u = 0; u < 2; ++u) {
        const size_t ga = aRow0 + (size_t)(u * 16) * 512 + koff + stSrc;
        const size_t gb = bRow0 + (size_t)(u * 16) * 512 + koff + stSrc;
        const int d = ur * 64 + u * 1024;
        STAGE16(xh + ga, wb + d);
        STAGE16(xl + ga, wb + 8192 + d);
        STAGE16(eh + gb, wb + 16384 + d);
        STAGE16(el + gb, wb + 24576 + d);
      }
    }

    bf16x8 a_h[4], a_l[4], b_h[4], b_l[4];
#pragma unroll
    for (int m = 0; m < 4; ++m) {
      a_h[m] = *(const bf16x8*)(rb + rdA + m * 1024);
      a_l[m] = *(const bf16x8*)(rb + 8192 + rdA + m * 1024);
    }
#pragma unroll
    for (int n = 0; n < 4; ++n) {
      b_h[n] = *(const bf16x8*)(rb + 16384 + rdB + n * 1024);
      b_l[n] = *(const bf16x8*)(rb + 24576 + rdB + n * 1024);
    }
    __builtin_amdgcn_s_setprio(1);
#pragma unroll
    for (int m = 0; m < 4; ++m)
#pragma unroll
      for (int n = 0; n < 4; ++n) {
        acc[m][n] = __builtin_amdgcn_mfma_f32_16x16x32_bf16(a_h[m], b_h[n], acc[m][n], 0, 0, 0);
        acc[m][n] = __builtin_amdgcn_mfma_f32_16x16x32_bf16(a_h[m], b_l[n], acc[m][n], 0, 0, 0);
        acc[m][n] = __builtin_amdgcn_mfma_f32_16x16x32_bf16(a_l[m], b_h[n], acc[m][n], 0, 0, 0);
      }
    __builtin_amdgcn_s_setprio(0);

    WAITVM0();     // next tile's 8 loads: issued ~300 cycles ago, mostly landed
    SBAR();
    cur ^= 1;
  }

  // epilogue: score = ||e||^2 - 2*dot ; per-row argmin -> 64-bit key atomicMin
  const float en[4] = {en0, en1, en2, en3};
  const int rowBase = bm * 128 + wr * 64 + ((lane >> 4) << 2);
#pragma unroll
  for (int m = 0; m < 4; ++m) {
#pragma unroll
    for (int r = 0; r < 4; ++r) {
      unsigned long long best = ~0ull;
#pragma unroll
      for (int n = 0; n < 4; ++n) {
        float sc = en[n] - 2.0f * acc[m][n][r];
        unsigned u = __float_as_uint(sc);
        u = (u & 0x80000000u) ? ~u : (u | 0x80000000u);   // order-preserving
        unsigned long long key = ((unsigned long long)u << 32) | (unsigned)(codeBase + n * 16);
        best = key < best ? key : best;
      }
#pragma unroll
      for (int mk = 1; mk <= 8; mk <<= 1) {               // min across 16-lane col group
        unsigned lo32 = (unsigned)best, hi32 = (unsigned)(best >> 32);
        lo32 = __shfl_xor(lo32, mk, 64);
        hi32 = __shfl_xor(hi32, mk, 64);
        unsigned long long o = ((unsigned long long)hi32 << 32) | lo32;
        best = o < best ? o : best;
      }
      if ((lane & 15) == 0) atomicMin(&keys[rowBase + m * 16 + r], best);
    }
  }
}

// ---------- gather q (exact f32), q_st out, per-row squared error ----------
__global__ void gather_k(const float* __restrict__ x, const float* __restrict__ embT,
                         const unsigned long long* __restrict__ keys,
                         float* __restrict__ qout, float* __restrict__ rowsum) {
  const int row = blockIdx.x;
  const int lane = threadIdx.x;
  const int idx = (int)(keys[row] & 0xffffffffull);
  float4 q  = reinterpret_cast<const float4*>(embT + (size_t)idx * DDIM)[lane];
  float4 xv = reinterpret_cast<const float4*>(x + (size_t)row * DDIM)[lane];
  reinterpret_cast<float4*>(qout + (size_t)row * DDIM)[lane] = q;
  float dx = q.x - xv.x, dy = q.y - xv.y, dz = q.z - xv.z, dw = q.w - xv.w;
  float s = dx * dx + dy * dy + dz * dz + dw * dw;
#pragma unroll
  for (int mk = 32; mk; mk >>= 1) s += __shfl_xor(s, mk, 64);
  if (lane == 0) rowsum[row] = s;
}

// ---------- deterministic final loss reduce ----------
__global__ void loss_k(const float* __restrict__ rowsum, float* __restrict__ out) {
  __shared__ float sm[4];
  const int t = threadIdx.x;
  float s = 0.f;
  for (int j = t; j < N_ROWS; j += 256) s += rowsum[j];
#pragma unroll
  for (int mk = 32; mk; mk >>= 1) s += __shfl_xor(s, mk, 64);
  if ((t & 63) == 0) sm[t >> 6] = s;
  __syncthreads();
  if (t == 0) out[0] = 2.0f * (sm[0] + sm[1] + sm[2] + sm[3]) / (float)(N_ROWS * DDIM);
}

extern "C" void kernel_launch(void* const* d_in, const int* in_sizes, int n_in,
                              void* d_out, int out_size, void* d_ws, size_t ws_size,
                              hipStream_t stream) {
  const float* x   = (const float*)d_in[0];          // [16,1024,256] f32
  const float* emb = (const float*)d_in[1];          // [256,8192] f32
  float* qout = (float*)d_out;                       // 4,194,304 q_st + 1 loss

  char* w = (char*)d_ws;
  unsigned long long* keys = (unsigned long long*)w;                 // 128 KB
  float* rowsum = (float*)(w + 131072);                              // 64 KB
  __bf16* xhi = (__bf16*)(w + 196608);                               // 8 MB
  __bf16* xlo = xhi + (size_t)N_ROWS * DDIM;                         // 8 MB
  __bf16* ehi = xlo + (size_t)N_ROWS * DDIM;                         // 4 MB
  __bf16* elo = ehi + (size_t)N_CODES * DDIM;                        // 4 MB
  float*  embT = (float*)(elo + (size_t)N_CODES * DDIM);             // 8 MB
  float*  enorm = embT + (size_t)N_CODES * DDIM;                     // 32 KB

  hipMemsetAsync(keys, 0xFF, N_ROWS * sizeof(unsigned long long), stream);
  prep_x_k<<<4096, 256, 0, stream>>>(x, xhi, xlo);
  prep_e_k<<<dim3(N_CODES / 64, DDIM / 64), 256, 0, stream>>>(emb, ehi, elo, embT);
  enorm_k<<<N_CODES / 256, 256, 0, stream>>>(emb, enorm);
  vq_main_k<<<8192, 256, 0, stream>>>(xhi, xlo, ehi, elo, enorm, keys);
  gather_k<<<N_ROWS, 64, 0, stream>>>(x, embT, keys, qout, rowsum);
  loss_k<<<1, 256, 0, stream>>>(rowsum, qout + (size_t)N_ROWS * DDIM);
}

// Round 5
// 272.873 us; speedup vs baseline: 1.2476x; 1.0897x over previous
//
#include <hip/hip_runtime.h>
#include <hip/hip_bf16.h>
#include <cstdint>

// VQ quantizer: dist argmin over 8192 codes, gather, loss.
// R5: 32x32x16 MFMA with SWAPPED operands (C[code][xrow]) so argmax is
// lane-local; -||e||^2/2 folded into acc init; wave tile 128x64 (block
// 256x128, BK=16) cuts LDS reads 25%; fragment-major linear LDS staging
// (lane-contiguous ds_read_b128, no swizzle). 3-pass hi/lo bf16 split kept.

typedef __bf16 bf16x8 __attribute__((ext_vector_type(8)));
typedef __bf16 bf16x4 __attribute__((ext_vector_type(4)));
typedef float  f32x16 __attribute__((ext_vector_type(16)));

#define N_ROWS  16384
#define N_CODES 8192
#define DDIM    256
#define NT      16             // 256 / BK16
#define BUFB    24576          // xh 8K | xl 8K | eh 4K | el 4K

#define STAGE16(gptr, lptr) __builtin_amdgcn_global_load_lds( \
    (const __attribute__((address_space(1))) void*)(gptr),    \
    (__attribute__((address_space(3))) void*)(lptr), 16, 0, 0)

#define SBAR() do { asm volatile("" ::: "memory"); \
                    __builtin_amdgcn_s_barrier();  \
                    asm volatile("" ::: "memory"); } while (0)
#define WAITVM0() asm volatile("s_waitcnt vmcnt(0)" ::: "memory")

// ---------- prep: split x (f32) into bf16 hi/lo planes ----------
__global__ void prep_x_k(const float* __restrict__ x,
                         __bf16* __restrict__ xhi, __bf16* __restrict__ xlo) {
  int i = blockIdx.x * 256 + threadIdx.x;
  float4 v = reinterpret_cast<const float4*>(x)[i];
  float a[4] = {v.x, v.y, v.z, v.w};
  bf16x4 h, l;
#pragma unroll
  for (int j = 0; j < 4; ++j) {
    __bf16 hh = (__bf16)a[j];
    h[j] = hh;
    l[j] = (__bf16)(a[j] - (float)hh);
  }
  reinterpret_cast<bf16x4*>(xhi)[i] = h;
  reinterpret_cast<bf16x4*>(xlo)[i] = l;
}

// ---------- prep: transpose emb [256][8192] -> [8192][256]; split + f32 copy ----------
__global__ void prep_e_k(const float* __restrict__ emb,
                         __bf16* __restrict__ ehi, __bf16* __restrict__ elo,
                         float* __restrict__ embT) {
  __shared__ float tile[64][65];
  const int kb = blockIdx.x * 64, db = blockIdx.y * 64;
  const int t = threadIdx.x;
  const int tk = t & 63, td = t >> 6;
#pragma unroll
  for (int c = 0; c < 16; ++c) {
    int d = c * 4 + td;
    tile[d][tk] = emb[(size_t)(db + d) * N_CODES + kb + tk];
  }
  __syncthreads();
#pragma unroll
  for (int c = 0; c < 16; ++c) {
    int k = c * 4 + td;
    int d = tk;
    float v = tile[d][k];
    size_t o = (size_t)(kb + k) * DDIM + db + d;
    __bf16 h = (__bf16)v;
    embT[o] = v;
    ehi[o] = h;
    elo[o] = (__bf16)(v - (float)h);
  }
}

// ---------- prep: ||e_k||^2 in exact f32 ----------
__global__ void enorm_k(const float* __restrict__ emb, float* __restrict__ enorm) {
  int k = blockIdx.x * 256 + threadIdx.x;
  float s = 0.f;
  for (int d = 0; d < DDIM; ++d) {
    float v = emb[(size_t)d * N_CODES + k];
    s += v * v;
  }
  enorm[k] = s;
}

// ---------- main: block 256x128, wave 128x64, BK=16, swapped 32x32x16 ----------
// LDS per buffer (fragment-major, lane-linear): unit u (1KB = 64 lanes x 16B):
//   u in [0,8):  xh mb=u   | [8,16): xl mb=u-8 | [16,20): eh nb | [20,24): el nb
// A-operand = e-frag (row=code=lane&31, k=(lane>>5)*8+j), B-operand = x-frag.
// C layout (m74): col(lane&31)=xrow, code=(reg&3)+8*(reg>>2)+4*(lane>>5).
__global__ __launch_bounds__(256, 2) void vq_main_k(
    const __bf16* __restrict__ xhi, const __bf16* __restrict__ xlo,
    const __bf16* __restrict__ ehi, const __bf16* __restrict__ elo,
    const float* __restrict__ enorm, unsigned long long* __restrict__ keys) {
  __shared__ alignas(16) unsigned char smem[2][BUFB];

  const int tid = threadIdx.x;
  const int wid = tid >> 6, lane = tid & 63;
  const int wr = wid >> 1, wc = wid & 1;       // wr: m-half(128 rows), wc: n-half(64 codes)
  const int l31 = lane & 31, lh = lane >> 5;

  // XCD swizzle: each XCD owns an 8-bm window (2048 rows, 1MB/plane-pair,
  // L2-resident) swept over all 64 bn panels. 4096 % 8 == 0 -> bijective.
  const int orig = blockIdx.x;
  const int j = orig >> 3;
  const int bm = (orig & 7) * 8 + (j & 7);     // 0..63
  const int bn = j >> 3;                       // 0..63

  // acc init = -||e||^2/2  (argmin dist == argmax(dot - en/2))
  const int cbase = bn * 128 + wc * 64 + lh * 4;
  f32x16 cin[2];
#pragma unroll
  for (int n = 0; n < 2; ++n)
#pragma unroll
    for (int q = 0; q < 4; ++q)
#pragma unroll
      for (int r = 0; r < 4; ++r)
        cin[n][q * 4 + r] = -0.5f * enorm[cbase + n * 32 + q * 8 + r];
  f32x16 acc[4][2];
#pragma unroll
  for (int m = 0; m < 4; ++m) { acc[m][0] = cin[0]; acc[m][1] = cin[1]; }

  const char* xph = (const char*)xhi; const char* xpl = (const char*)xlo;
  const char* eph = (const char*)ehi; const char* epl = (const char*)elo;
  const size_t aB = (size_t)bm * 256 * 512;    // bytes
  const size_t bB = (size_t)bn * 128 * 512;
  const size_t laneOff = (size_t)l31 * 512 + (size_t)lh * 16;

  // fragment read offsets (lane-linear)
  const int xoff = (wr * 4) * 1024 + lane * 16;          // +m*1024; xl: +8192
  const int eoff = 16384 + (wc * 2) * 1024 + lane * 16;  // +n*1024; el: +4096

  unsigned char* s0 = &smem[0][0];

#define STAGE_TILE(buf, kb) do {                                               \
  _Pragma("unroll")                                                            \
  for (int i_ = 0; i_ < 6; ++i_) {                                             \
    const int u_ = wid + 4 * i_;                                               \
    const char* s_;                                                            \
    if (u_ < 16) s_ = (u_ < 8 ? xph : xpl) + aB + (size_t)(u_ & 7) * 16384 + laneOff + (kb); \
    else         s_ = (u_ < 20 ? eph : epl) + bB + (size_t)(u_ & 3) * 16384 + laneOff + (kb); \
    STAGE16(s_, (buf) + u_ * 1024);                                            \
  } } while (0)

  // prologue: tile 0 -> buf 0
  STAGE_TILE(s0, (size_t)0);
  WAITVM0();
  SBAR();

  int cur = 0;
#pragma unroll 1
  for (int t = 0; t < NT; ++t) {
    const unsigned char* rb = s0 + cur * BUFB;
    unsigned char* wb = s0 + (cur ^ 1) * BUFB;

    if (t < NT - 1) STAGE_TILE(wb, (size_t)(t + 1) * 32);

    bf16x8 xhf[4], xlf[4], ehf[2], elf[2];
#pragma unroll
    for (int m = 0; m < 4; ++m) {
      xhf[m] = *(const bf16x8*)(rb + xoff + m * 1024);
      xlf[m] = *(const bf16x8*)(rb + 8192 + xoff + m * 1024);
    }
#pragma unroll
    for (int n = 0; n < 2; ++n) {
      ehf[n] = *(const bf16x8*)(rb + eoff + n * 1024);
      elf[n] = *(const bf16x8*)(rb + 4096 + eoff + n * 1024);
    }
    __builtin_amdgcn_s_setprio(1);
#pragma unroll
    for (int m = 0; m < 4; ++m)
#pragma unroll
      for (int n = 0; n < 2; ++n) {
        acc[m][n] = __builtin_amdgcn_mfma_f32_32x32x16_bf16(ehf[n], xhf[m], acc[m][n], 0, 0, 0);
        acc[m][n] = __builtin_amdgcn_mfma_f32_32x32x16_bf16(ehf[n], xlf[m], acc[m][n], 0, 0, 0);
        acc[m][n] = __builtin_amdgcn_mfma_f32_32x32x16_bf16(elf[n], xhf[m], acc[m][n], 0, 0, 0);
      }
    __builtin_amdgcn_s_setprio(0);

    WAITVM0();
    SBAR();
    cur ^= 1;
  }

  // epilogue: per lane, x-row = bm*256 + (wr*4+m)*32 + l31 holds 32 scores.
  // Ascending-code scan w/ strict > keeps smallest code on ties (numpy argmin).
#pragma unroll
  for (int m = 0; m < 4; ++m) {
    float bv = -3.4e38f;
    unsigned bcode = 0;
#pragma unroll
    for (int n = 0; n < 2; ++n)
#pragma unroll
      for (int q = 0; q < 4; ++q)
#pragma unroll
        for (int r = 0; r < 4; ++r) {
          float v = acc[m][n][q * 4 + r];
          unsigned c = (unsigned)(cbase + n * 32 + q * 8 + r);
          if (v > bv) { bv = v; bcode = c; }
        }
    unsigned u = __float_as_uint(bv);
    u = (u & 0x80000000u) ? ~u : (u | 0x80000000u);        // order-preserving
    unsigned long long key =
        ((unsigned long long)u << 32) | (unsigned)(0xFFFFFFFFu ^ bcode);
    unsigned olo = __shfl_xor((unsigned)key, 32, 64);
    unsigned ohi = __shfl_xor((unsigned)(key >> 32), 32, 64);
    unsigned long long okey = ((unsigned long long)ohi << 32) | olo;
    if (okey > key) key = okey;
    if (lane < 32)
      atomicMax(&keys[bm * 256 + (wr * 4 + m) * 32 + l31], key);
  }
#undef STAGE_TILE
}

// ---------- gather q (exact f32), q_st out, per-row squared error ----------
__global__ void gather_k(const float* __restrict__ x, const float* __restrict__ embT,
                         const unsigned long long* __restrict__ keys,
                         float* __restrict__ qout, float* __restrict__ rowsum) {
  const int row = blockIdx.x;
  const int lane = threadIdx.x;
  const unsigned low = (unsigned)(keys[row] & 0xffffffffull);
  const int idx = (int)(~low);                 // stored 0xFFFFFFFF ^ code
  float4 q  = reinterpret_cast<const float4*>(embT + (size_t)idx * DDIM)[lane];
  float4 xv = reinterpret_cast<const float4*>(x + (size_t)row * DDIM)[lane];
  reinterpret_cast<float4*>(qout + (size_t)row * DDIM)[lane] = q;
  float dx = q.x - xv.x, dy = q.y - xv.y, dz = q.z - xv.z, dw = q.w - xv.w;
  float s = dx * dx + dy * dy + dz * dz + dw * dw;
#pragma unroll
  for (int mk = 32; mk; mk >>= 1) s += __shfl_xor(s, mk, 64);
  if (lane == 0) rowsum[row] = s;
}

// ---------- deterministic final loss reduce ----------
__global__ void loss_k(const float* __restrict__ rowsum, float* __restrict__ out) {
  __shared__ float sm[4];
  const int t = threadIdx.x;
  float s = 0.f;
  for (int j = t; j < N_ROWS; j += 256) s += rowsum[j];
#pragma unroll
  for (int mk = 32; mk; mk >>= 1) s += __shfl_xor(s, mk, 64);
  if ((t & 63) == 0) sm[t >> 6] = s;
  __syncthreads();
  if (t == 0) out[0] = 2.0f * (sm[0] + sm[1] + sm[2] + sm[3]) / (float)(N_ROWS * DDIM);
}

extern "C" void kernel_launch(void* const* d_in, const int* in_sizes, int n_in,
                              void* d_out, int out_size, void* d_ws, size_t ws_size,
                              hipStream_t stream) {
  const float* x   = (const float*)d_in[0];          // [16,1024,256] f32
  const float* emb = (const float*)d_in[1];          // [256,8192] f32
  float* qout = (float*)d_out;                       // 4,194,304 q_st + 1 loss

  char* w = (char*)d_ws;
  unsigned long long* keys = (unsigned long long*)w;                 // 128 KB
  float* rowsum = (float*)(w + 131072);                              // 64 KB
  __bf16* xhi = (__bf16*)(w + 196608);                               // 8 MB
  __bf16* xlo = xhi + (size_t)N_ROWS * DDIM;                         // 8 MB
  __bf16* ehi = xlo + (size_t)N_ROWS * DDIM;                         // 4 MB
  __bf16* elo = ehi + (size_t)N_CODES * DDIM;                        // 4 MB
  float*  embT = (float*)(elo + (size_t)N_CODES * DDIM);             // 8 MB
  float*  enorm = embT + (size_t)N_CODES * DDIM;                     // 32 KB

  hipMemsetAsync(keys, 0, N_ROWS * sizeof(unsigned long long), stream);  // atomicMax
  prep_x_k<<<4096, 256, 0, stream>>>(x, xhi, xlo);
  prep_e_k<<<dim3(N_CODES / 64, DDIM / 64), 256, 0, stream>>>(emb, ehi, elo, embT);
  enorm_k<<<N_CODES / 256, 256, 0, stream>>>(emb, enorm);
  vq_main_k<<<4096, 256, 0, stream>>>(xhi, xlo, ehi, elo, enorm, keys);
  gather_k<<<N_ROWS, 64, 0, stream>>>(x, embT, keys, qout, rowsum);
  loss_k<<<1, 256, 0, stream>>>(rowsum, qout + (size_t)N_ROWS * DDIM);
}

// Round 6
// 272.028 us; speedup vs baseline: 1.2515x; 1.0031x over previous
//
#include <hip/hip_runtime.h>
#include <hip/hip_bf16.h>
#include <cstdint>

// VQ quantizer: dist argmin over 8192 codes, gather, loss.
// R6: R5 structure with PASS-MAJOR MFMA ordering — all 8 independent MFMAs of
// each hi/lo pass issue consecutively (reuse distance 8 ≈ 256 cyc) instead of
// dependent 3-chains on the same acc (the latency stall capping MfmaUtil at
// 36%). ds_reads split into hi-cluster / lo-cluster to overlap with MFMA.

typedef __bf16 bf16x8 __attribute__((ext_vector_type(8)));
typedef __bf16 bf16x4 __attribute__((ext_vector_type(4)));
typedef float  f32x16 __attribute__((ext_vector_type(16)));

#define N_ROWS  16384
#define N_CODES 8192
#define DDIM    256
#define NT      16             // 256 / BK16
#define BUFB    24576          // xh 8K | xl 8K | eh 4K | el 4K

#define STAGE16(gptr, lptr) __builtin_amdgcn_global_load_lds( \
    (const __attribute__((address_space(1))) void*)(gptr),    \
    (__attribute__((address_space(3))) void*)(lptr), 16, 0, 0)

#define SBAR() do { asm volatile("" ::: "memory"); \
                    __builtin_amdgcn_s_barrier();  \
                    asm volatile("" ::: "memory"); } while (0)
#define WAITVM0() asm volatile("s_waitcnt vmcnt(0)" ::: "memory")

// ---------- prep: split x (f32) into bf16 hi/lo planes ----------
__global__ void prep_x_k(const float* __restrict__ x,
                         __bf16* __restrict__ xhi, __bf16* __restrict__ xlo) {
  int i = blockIdx.x * 256 + threadIdx.x;
  float4 v = reinterpret_cast<const float4*>(x)[i];
  float a[4] = {v.x, v.y, v.z, v.w};
  bf16x4 h, l;
#pragma unroll
  for (int j = 0; j < 4; ++j) {
    __bf16 hh = (__bf16)a[j];
    h[j] = hh;
    l[j] = (__bf16)(a[j] - (float)hh);
  }
  reinterpret_cast<bf16x4*>(xhi)[i] = h;
  reinterpret_cast<bf16x4*>(xlo)[i] = l;
}

// ---------- prep: transpose emb [256][8192] -> [8192][256]; split + f32 copy ----------
__global__ void prep_e_k(const float* __restrict__ emb,
                         __bf16* __restrict__ ehi, __bf16* __restrict__ elo,
                         float* __restrict__ embT) {
  __shared__ float tile[64][65];
  const int kb = blockIdx.x * 64, db = blockIdx.y * 64;
  const int t = threadIdx.x;
  const int tk = t & 63, td = t >> 6;
#pragma unroll
  for (int c = 0; c < 16; ++c) {
    int d = c * 4 + td;
    tile[d][tk] = emb[(size_t)(db + d) * N_CODES + kb + tk];
  }
  __syncthreads();
#pragma unroll
  for (int c = 0; c < 16; ++c) {
    int k = c * 4 + td;
    int d = tk;
    float v = tile[d][k];
    size_t o = (size_t)(kb + k) * DDIM + db + d;
    __bf16 h = (__bf16)v;
    embT[o] = v;
    ehi[o] = h;
    elo[o] = (__bf16)(v - (float)h);
  }
}

// ---------- prep: ||e_k||^2 in exact f32 ----------
__global__ void enorm_k(const float* __restrict__ emb, float* __restrict__ enorm) {
  int k = blockIdx.x * 256 + threadIdx.x;
  float s = 0.f;
  for (int d = 0; d < DDIM; ++d) {
    float v = emb[(size_t)d * N_CODES + k];
    s += v * v;
  }
  enorm[k] = s;
}

// ---------- main: block 256x128, wave 128x64, BK=16, swapped 32x32x16 ----------
// LDS per buffer (fragment-major, lane-linear): unit u (1KB = 64 lanes x 16B):
//   u in [0,8):  xh mb=u   | [8,16): xl mb=u-8 | [16,20): eh nb | [20,24): el nb
// A-operand = e-frag (row=code=lane&31, k=(lane>>5)*8+j), B-operand = x-frag.
// C layout (m74): col(lane&31)=xrow, code=(reg&3)+8*(reg>>2)+4*(lane>>5).
__global__ __launch_bounds__(256, 2) void vq_main_k(
    const __bf16* __restrict__ xhi, const __bf16* __restrict__ xlo,
    const __bf16* __restrict__ ehi, const __bf16* __restrict__ elo,
    const float* __restrict__ enorm, unsigned long long* __restrict__ keys) {
  __shared__ alignas(16) unsigned char smem[2][BUFB];

  const int tid = threadIdx.x;
  const int wid = tid >> 6, lane = tid & 63;
  const int wr = wid >> 1, wc = wid & 1;       // wr: m-half(128 rows), wc: n-half(64 codes)
  const int l31 = lane & 31, lh = lane >> 5;

  // XCD swizzle: each XCD owns an 8-bm window (2048 rows, L2-resident)
  // swept over all 64 bn panels. 4096 % 8 == 0 -> bijective.
  const int orig = blockIdx.x;
  const int j = orig >> 3;
  const int bm = (orig & 7) * 8 + (j & 7);     // 0..63
  const int bn = j >> 3;                       // 0..63

  // acc init = -||e||^2/2  (argmin dist == argmax(dot - en/2))
  const int cbase = bn * 128 + wc * 64 + lh * 4;
  f32x16 cin[2];
#pragma unroll
  for (int n = 0; n < 2; ++n)
#pragma unroll
    for (int q = 0; q < 4; ++q)
#pragma unroll
      for (int r = 0; r < 4; ++r)
        cin[n][q * 4 + r] = -0.5f * enorm[cbase + n * 32 + q * 8 + r];
  f32x16 acc[4][2];
#pragma unroll
  for (int m = 0; m < 4; ++m) { acc[m][0] = cin[0]; acc[m][1] = cin[1]; }

  const char* xph = (const char*)xhi; const char* xpl = (const char*)xlo;
  const char* eph = (const char*)ehi; const char* epl = (const char*)elo;
  const size_t aB = (size_t)bm * 256 * 512;    // bytes
  const size_t bB = (size_t)bn * 128 * 512;
  const size_t laneOff = (size_t)l31 * 512 + (size_t)lh * 16;

  // fragment read offsets (lane-linear)
  const int xoff = (wr * 4) * 1024 + lane * 16;          // +m*1024; xl: +8192
  const int eoff = 16384 + (wc * 2) * 1024 + lane * 16;  // +n*1024; el: +4096

  unsigned char* s0 = &smem[0][0];

#define STAGE_TILE(buf, kb) do {                                               \
  _Pragma("unroll")                                                            \
  for (int i_ = 0; i_ < 6; ++i_) {                                             \
    const int u_ = wid + 4 * i_;                                               \
    const char* s_;                                                            \
    if (u_ < 16) s_ = (u_ < 8 ? xph : xpl) + aB + (size_t)(u_ & 7) * 16384 + laneOff + (kb); \
    else         s_ = (u_ < 20 ? eph : epl) + bB + (size_t)(u_ & 3) * 16384 + laneOff + (kb); \
    STAGE16(s_, (buf) + u_ * 1024);                                            \
  } } while (0)

  // prologue: tile 0 -> buf 0
  STAGE_TILE(s0, (size_t)0);
  WAITVM0();
  SBAR();

  int cur = 0;
#pragma unroll 1
  for (int t = 0; t < NT; ++t) {
    const unsigned char* rb = s0 + cur * BUFB;
    unsigned char* wb = s0 + (cur ^ 1) * BUFB;

    if (t < NT - 1) STAGE_TILE(wb, (size_t)(t + 1) * 32);

    // ---- hi-fragment cluster + pass 1 (e_hi x x_hi): 8 independent MFMAs ----
    bf16x8 ehf[2], xhf[4];
#pragma unroll
    for (int n = 0; n < 2; ++n) ehf[n] = *(const bf16x8*)(rb + eoff + n * 1024);
#pragma unroll
    for (int m = 0; m < 4; ++m) xhf[m] = *(const bf16x8*)(rb + xoff + m * 1024);
    __builtin_amdgcn_s_setprio(1);
#pragma unroll
    for (int m = 0; m < 4; ++m)
#pragma unroll
      for (int n = 0; n < 2; ++n)
        acc[m][n] = __builtin_amdgcn_mfma_f32_32x32x16_bf16(ehf[n], xhf[m], acc[m][n], 0, 0, 0);
    __builtin_amdgcn_s_setprio(0);

    // ---- lo-fragment cluster + pass 2 (e_hi x x_lo) + pass 3 (e_lo x x_hi) ----
    bf16x8 elf[2], xlf[4];
#pragma unroll
    for (int n = 0; n < 2; ++n) elf[n] = *(const bf16x8*)(rb + 4096 + eoff + n * 1024);
#pragma unroll
    for (int m = 0; m < 4; ++m) xlf[m] = *(const bf16x8*)(rb + 8192 + xoff + m * 1024);
    __builtin_amdgcn_s_setprio(1);
#pragma unroll
    for (int m = 0; m < 4; ++m)
#pragma unroll
      for (int n = 0; n < 2; ++n)
        acc[m][n] = __builtin_amdgcn_mfma_f32_32x32x16_bf16(ehf[n], xlf[m], acc[m][n], 0, 0, 0);
#pragma unroll
    for (int m = 0; m < 4; ++m)
#pragma unroll
      for (int n = 0; n < 2; ++n)
        acc[m][n] = __builtin_amdgcn_mfma_f32_32x32x16_bf16(elf[n], xhf[m], acc[m][n], 0, 0, 0);
    __builtin_amdgcn_s_setprio(0);

    WAITVM0();
    SBAR();
    cur ^= 1;
  }

  // epilogue: per lane, x-row = bm*256 + (wr*4+m)*32 + l31 holds 32 scores.
  // Ascending-code scan w/ strict > keeps smallest code on ties (numpy argmin).
#pragma unroll
  for (int m = 0; m < 4; ++m) {
    float bv = -3.4e38f;
    unsigned bcode = 0;
#pragma unroll
    for (int n = 0; n < 2; ++n)
#pragma unroll
      for (int q = 0; q < 4; ++q)
#pragma unroll
        for (int r = 0; r < 4; ++r) {
          float v = acc[m][n][q * 4 + r];
          unsigned c = (unsigned)(cbase + n * 32 + q * 8 + r);
          if (v > bv) { bv = v; bcode = c; }
        }
    unsigned u = __float_as_uint(bv);
    u = (u & 0x80000000u) ? ~u : (u | 0x80000000u);        // order-preserving
    unsigned long long key =
        ((unsigned long long)u << 32) | (unsigned)(0xFFFFFFFFu ^ bcode);
    unsigned olo = __shfl_xor((unsigned)key, 32, 64);
    unsigned ohi = __shfl_xor((unsigned)(key >> 32), 32, 64);
    unsigned long long okey = ((unsigned long long)ohi << 32) | olo;
    if (okey > key) key = okey;
    if (lane < 32)
      atomicMax(&keys[bm * 256 + (wr * 4 + m) * 32 + l31], key);
  }
#undef STAGE_TILE
}

// ---------- gather q (exact f32), q_st out, per-row squared error ----------
__global__ void gather_k(const float* __restrict__ x, const float* __restrict__ embT,
                         const unsigned long long* __restrict__ keys,
                         float* __restrict__ qout, float* __restrict__ rowsum) {
  const int row = blockIdx.x;
  const int lane = threadIdx.x;
  const unsigned low = (unsigned)(keys[row] & 0xffffffffull);
  const int idx = (int)(~low);                 // stored 0xFFFFFFFF ^ code
  float4 q  = reinterpret_cast<const float4*>(embT + (size_t)idx * DDIM)[lane];
  float4 xv = reinterpret_cast<const float4*>(x + (size_t)row * DDIM)[lane];
  reinterpret_cast<float4*>(qout + (size_t)row * DDIM)[lane] = q;
  float dx = q.x - xv.x, dy = q.y - xv.y, dz = q.z - xv.z, dw = q.w - xv.w;
  float s = dx * dx + dy * dy + dz * dz + dw * dw;
#pragma unroll
  for (int mk = 32; mk; mk >>= 1) s += __shfl_xor(s, mk, 64);
  if (lane == 0) rowsum[row] = s;
}

// ---------- deterministic final loss reduce ----------
__global__ void loss_k(const float* __restrict__ rowsum, float* __restrict__ out) {
  __shared__ float sm[4];
  const int t = threadIdx.x;
  float s = 0.f;
  for (int j = t; j < N_ROWS; j += 256) s += rowsum[j];
#pragma unroll
  for (int mk = 32; mk; mk >>= 1) s += __shfl_xor(s, mk, 64);
  if ((t & 63) == 0) sm[t >> 6] = s;
  __syncthreads();
  if (t == 0) out[0] = 2.0f * (sm[0] + sm[1] + sm[2] + sm[3]) / (float)(N_ROWS * DDIM);
}

extern "C" void kernel_launch(void* const* d_in, const int* in_sizes, int n_in,
                              void* d_out, int out_size, void* d_ws, size_t ws_size,
                              hipStream_t stream) {
  const float* x   = (const float*)d_in[0];          // [16,1024,256] f32
  const float* emb = (const float*)d_in[1];          // [256,8192] f32
  float* qout = (float*)d_out;                       // 4,194,304 q_st + 1 loss

  char* w = (char*)d_ws;
  unsigned long long* keys = (unsigned long long*)w;                 // 128 KB
  float* rowsum = (float*)(w + 131072);                              // 64 KB
  __bf16* xhi = (__bf16*)(w + 196608);                               // 8 MB
  __bf16* xlo = xhi + (size_t)N_ROWS * DDIM;                         // 8 MB
  __bf16* ehi = xlo + (size_t)N_ROWS * DDIM;                         // 4 MB
  __bf16* elo = ehi + (size_t)N_CODES * DDIM;                        // 4 MB
  float*  embT = (float*)(elo + (size_t)N_CODES * DDIM);             // 8 MB
  float*  enorm = embT + (size_t)N_CODES * DDIM;                     // 32 KB

  hipMemsetAsync(keys, 0, N_ROWS * sizeof(unsigned long long), stream);  // atomicMax
  prep_x_k<<<4096, 256, 0, stream>>>(x, xhi, xlo);
  prep_e_k<<<dim3(N_CODES / 64, DDIM / 64), 256, 0, stream>>>(emb, ehi, elo, embT);
  enorm_k<<<N_CODES / 256, 256, 0, stream>>>(emb, enorm);
  vq_main_k<<<4096, 256, 0, stream>>>(xhi, xlo, ehi, elo, enorm, keys);
  gather_k<<<N_ROWS, 64, 0, stream>>>(x, embT, keys, qout, rowsum);
  loss_k<<<1, 256, 0, stream>>>(rowsum, qout + (size_t)N_ROWS * DDIM);
}

// Round 7
// 246.482 us; speedup vs baseline: 1.3812x; 1.1036x over previous
//
#include <hip/hip_runtime.h>
#include <hip/hip_bf16.h>
#include <cstdint>

// VQ quantizer: dist argmin over 8192 codes, gather, loss.
// R7: m201-style phase schedule on the R5/R6 math core. Block 512thr/8 waves,
// tile 256 codes x 256 rows, BK=16, NT=16, 3x32KB LDS rotation, counted
// vmcnt(4) at step end (loads for t+2 stay in flight across barriers),
// 3 phases/step {ds_read || stage -> bar -> lgkm0 -> prio1 -> 8 MFMA -> prio0
// -> bar}. Fragment-major lane-linear LDS (conflict-free, no swizzle).

typedef __bf16 bf16x8 __attribute__((ext_vector_type(8)));
typedef __bf16 bf16x4 __attribute__((ext_vector_type(4)));
typedef float  f32x16 __attribute__((ext_vector_type(16)));

#define N_ROWS  16384
#define N_CODES 8192
#define DDIM    256
#define NT      16             // 256 / BK16
#define BUFB    32768          // xh 8K | xl 8K | eh 8K | el 8K

#define STAGE16(gptr, lptr) __builtin_amdgcn_global_load_lds( \
    (const __attribute__((address_space(1))) void*)(gptr),    \
    (__attribute__((address_space(3))) void*)(lptr), 16, 0, 0)

#define SBAR() do { asm volatile("" ::: "memory"); \
                    __builtin_amdgcn_s_barrier();  \
                    asm volatile("" ::: "memory"); } while (0)
#define WAITVM(N) asm volatile("s_waitcnt vmcnt(" #N ")" ::: "memory")
#define LGKM0() do { asm volatile("s_waitcnt lgkmcnt(0)" ::: "memory"); \
                     __builtin_amdgcn_sched_barrier(0); } while (0)

// ---------- prep: split x (f32) into bf16 hi/lo planes ----------
__global__ void prep_x_k(const float* __restrict__ x,
                         __bf16* __restrict__ xhi, __bf16* __restrict__ xlo) {
  int i = blockIdx.x * 256 + threadIdx.x;
  float4 v = reinterpret_cast<const float4*>(x)[i];
  float a[4] = {v.x, v.y, v.z, v.w};
  bf16x4 h, l;
#pragma unroll
  for (int j = 0; j < 4; ++j) {
    __bf16 hh = (__bf16)a[j];
    h[j] = hh;
    l[j] = (__bf16)(a[j] - (float)hh);
  }
  reinterpret_cast<bf16x4*>(xhi)[i] = h;
  reinterpret_cast<bf16x4*>(xlo)[i] = l;
}

// ---------- prep: transpose emb [256][8192] -> [8192][256]; split + f32 copy ----------
__global__ void prep_e_k(const float* __restrict__ emb,
                         __bf16* __restrict__ ehi, __bf16* __restrict__ elo,
                         float* __restrict__ embT) {
  __shared__ float tile[64][65];
  const int kb = blockIdx.x * 64, db = blockIdx.y * 64;
  const int t = threadIdx.x;
  const int tk = t & 63, td = t >> 6;
#pragma unroll
  for (int c = 0; c < 16; ++c) {
    int d = c * 4 + td;
    tile[d][tk] = emb[(size_t)(db + d) * N_CODES + kb + tk];
  }
  __syncthreads();
#pragma unroll
  for (int c = 0; c < 16; ++c) {
    int k = c * 4 + td;
    int d = tk;
    float v = tile[d][k];
    size_t o = (size_t)(kb + k) * DDIM + db + d;
    __bf16 h = (__bf16)v;
    embT[o] = v;
    ehi[o] = h;
    elo[o] = (__bf16)(v - (float)h);
  }
}

// ---------- prep: ||e_k||^2 in exact f32 ----------
__global__ void enorm_k(const float* __restrict__ emb, float* __restrict__ enorm) {
  int k = blockIdx.x * 256 + threadIdx.x;
  float s = 0.f;
  for (int d = 0; d < DDIM; ++d) {
    float v = emb[(size_t)d * N_CODES + k];
    s += v * v;
  }
  enorm[k] = s;
}

// ---------- main: 256x256 tile, 8 waves, BK=16, 3-buf counted-vmcnt pipeline ----
// LDS buffer (32KB), 1KB units (64 lanes x 16B, one frag each):
//   [0,8): xh row-unit | [8,16): xl | [16,24): eh code-unit | [24,32): el
// Wave w stages units {xh[w], eh[w], xl[w], el[w]} (1KB each) per step.
// A-operand = e-frag (code=lane&31, k-chunk=lane>>5), B-operand = x-frag.
// C layout (m74): col(lane&31)=xrow, code=(reg&3)+8*(reg>>2)+4*(lane>>5).
__global__ __launch_bounds__(512, 2) void vq_main_k(
    const __bf16* __restrict__ xhi, const __bf16* __restrict__ xlo,
    const __bf16* __restrict__ ehi, const __bf16* __restrict__ elo,
    const float* __restrict__ enorm, unsigned long long* __restrict__ keys) {
  extern __shared__ __align__(16) unsigned char smem[];   // 3 * 32KB

  const int tid = threadIdx.x;
  const int wid = tid >> 6, lane = tid & 63;
  const int cg = wid >> 2, rg = wid & 3;      // code-half, row-quarter
  const int l31 = lane & 31, lh = lane >> 5;

  // XCD swizzle: each XCD owns an 8-bm window (2048 rows, L2-resident)
  // swept over all 32 bn panels. 2048 % 8 == 0 -> bijective.
  const int orig = blockIdx.x;
  const int j = orig >> 3;
  const int bm = (orig & 7) * 8 + (j & 7);    // 0..63
  const int bn = j >> 3;                      // 0..31

  // acc init = -||e||^2/2  (argmin dist == argmax(dot - en/2))
  const int cbase = bn * 256 + cg * 128 + lh * 4;
  f32x16 acc[4][2];
#pragma unroll
  for (int c = 0; c < 4; ++c) {
    f32x16 ci;
#pragma unroll
    for (int q = 0; q < 4; ++q)
#pragma unroll
      for (int r = 0; r < 4; ++r)
        ci[q * 4 + r] = -0.5f * enorm[cbase + c * 32 + q * 8 + r];
    acc[c][0] = ci; acc[c][1] = ci;
  }
  __builtin_amdgcn_sched_barrier(0);   // enorm waits resolve before staging

  // staging sources (wave-owned row/code unit = wid)
  const size_t aoff = (size_t)(bm * 256 + wid * 32 + l31) * 512 + (size_t)lh * 16;
  const size_t boff = (size_t)(bn * 256 + wid * 32 + l31) * 512 + (size_t)lh * 16;
  const char* pxh = (const char*)xhi + aoff;
  const char* pxl = (const char*)xlo + aoff;
  const char* peh = (const char*)ehi + boff;
  const char* pel = (const char*)elo + boff;
  const int dxh = wid * 1024, dxl = 8192 + wid * 1024;
  const int deh = 16384 + wid * 1024, del = 24576 + wid * 1024;

  // fragment read offsets (lane-linear)
  const int xrd = rg * 2048 + lane * 16;           // + r*1024 ; xl at +8192
  const int erd = 16384 + cg * 4096 + lane * 16;   // + c*1024 ; el at +8192

  unsigned char* b0 = smem;
  unsigned char* b1 = smem + BUFB;
  unsigned char* b2 = smem + 2 * BUFB;

  // prologue: step 0 -> buf0, step 1 -> buf1 (4 loads each per wave)
  STAGE16(pxh, b0 + dxh); STAGE16(peh, b0 + deh);
  STAGE16(pxl, b0 + dxl); STAGE16(pel, b0 + del);
  STAGE16(pxh + 32, b1 + dxh); STAGE16(peh + 32, b1 + deh);
  STAGE16(pxl + 32, b1 + dxl); STAGE16(pel + 32, b1 + del);
  WAITVM(4);          // step 0 landed; step 1's 4 in flight
  SBAR();

#pragma unroll 1
  for (int t = 0; t < NT; ++t) {
    int s = t + 2; if (s >= NT) s -= NT;     // wrap keeps vmcnt counts uniform
    const size_t kb = (size_t)s * 32;

    // ---- phase 1: read eh(4) + xh(2), stage xh+eh of t+2, 8 MFMA hh ----
    bf16x8 ehf[4], xhf[2];
#pragma unroll
    for (int c = 0; c < 4; ++c) ehf[c] = *(const bf16x8*)(b0 + erd + c * 1024);
#pragma unroll
    for (int r = 0; r < 2; ++r) xhf[r] = *(const bf16x8*)(b0 + xrd + r * 1024);
    STAGE16(pxh + kb, b2 + dxh);
    STAGE16(peh + kb, b2 + deh);
    SBAR();
    LGKM0();
    __builtin_amdgcn_s_setprio(1);
#pragma unroll
    for (int c = 0; c < 4; ++c)
#pragma unroll
      for (int r = 0; r < 2; ++r)
        acc[c][r] = __builtin_amdgcn_mfma_f32_32x32x16_bf16(ehf[c], xhf[r], acc[c][r], 0, 0, 0);
    __builtin_amdgcn_s_setprio(0);
    SBAR();

    // ---- phase 2: read xl(2), stage xl of t+2, 8 MFMA hl ----
    bf16x8 xlf[2];
#pragma unroll
    for (int r = 0; r < 2; ++r) xlf[r] = *(const bf16x8*)(b0 + 8192 + xrd + r * 1024);
    STAGE16(pxl + kb, b2 + dxl);
    SBAR();
    LGKM0();
    __builtin_amdgcn_s_setprio(1);
#pragma unroll
    for (int c = 0; c < 4; ++c)
#pragma unroll
      for (int r = 0; r < 2; ++r)
        acc[c][r] = __builtin_amdgcn_mfma_f32_32x32x16_bf16(ehf[c], xlf[r], acc[c][r], 0, 0, 0);
    __builtin_amdgcn_s_setprio(0);
    SBAR();

    // ---- phase 3: read el(4), stage el of t+2, 8 MFMA lh; counted vmcnt ----
    bf16x8 elf[4];
#pragma unroll
    for (int c = 0; c < 4; ++c) elf[c] = *(const bf16x8*)(b0 + 8192 + erd + c * 1024);
    STAGE16(pel + kb, b2 + del);
    SBAR();
    LGKM0();
    __builtin_amdgcn_s_setprio(1);
#pragma unroll
    for (int c = 0; c < 4; ++c)
#pragma unroll
      for (int r = 0; r < 2; ++r)
        acc[c][r] = __builtin_amdgcn_mfma_f32_32x32x16_bf16(elf[c], xhf[r], acc[c][r], 0, 0, 0);
    __builtin_amdgcn_s_setprio(0);
    WAITVM(4);       // t+1's buffer complete; t+2's 4 loads stay in flight
    SBAR();

    unsigned char* bt = b0; b0 = b1; b1 = b2; b2 = bt;
  }
  WAITVM(0);         // drain wrapped tail stages before LDS teardown

  // epilogue: per lane, xrow = bm*256 + rg*64 + r*32 + l31 holds 128 scores
  // (4 code-frags x 32). Ascending-code scan, strict > -> smallest code on tie.
#pragma unroll
  for (int r = 0; r < 2; ++r) {
    float bv = -3.4e38f;
    unsigned bcode = 0;
#pragma unroll
    for (int c = 0; c < 4; ++c)
#pragma unroll
      for (int q = 0; q < 4; ++q)
#pragma unroll
        for (int rr = 0; rr < 4; ++rr) {
          float v = acc[c][r][q * 4 + rr];
          unsigned cd = (unsigned)(cbase + c * 32 + q * 8 + rr);
          if (v > bv) { bv = v; bcode = cd; }
        }
    unsigned u = __float_as_uint(bv);
    u = (u & 0x80000000u) ? ~u : (u | 0x80000000u);        // order-preserving
    unsigned long long key =
        ((unsigned long long)u << 32) | (unsigned)(0xFFFFFFFFu ^ bcode);
    unsigned olo = __shfl_xor((unsigned)key, 32, 64);
    unsigned ohi = __shfl_xor((unsigned)(key >> 32), 32, 64);
    unsigned long long okey = ((unsigned long long)ohi << 32) | olo;
    if (okey > key) key = okey;
    if (lane < 32)
      atomicMax(&keys[bm * 256 + rg * 64 + r * 32 + l31], key);
  }
}

// ---------- gather q (exact f32), q_st out, per-row squared error ----------
__global__ void gather_k(const float* __restrict__ x, const float* __restrict__ embT,
                         const unsigned long long* __restrict__ keys,
                         float* __restrict__ qout, float* __restrict__ rowsum) {
  const int row = blockIdx.x;
  const int lane = threadIdx.x;
  const unsigned low = (unsigned)(keys[row] & 0xffffffffull);
  const int idx = (int)(~low);                 // stored 0xFFFFFFFF ^ code
  float4 q  = reinterpret_cast<const float4*>(embT + (size_t)idx * DDIM)[lane];
  float4 xv = reinterpret_cast<const float4*>(x + (size_t)row * DDIM)[lane];
  reinterpret_cast<float4*>(qout + (size_t)row * DDIM)[lane] = q;
  float dx = q.x - xv.x, dy = q.y - xv.y, dz = q.z - xv.z, dw = q.w - xv.w;
  float s = dx * dx + dy * dy + dz * dz + dw * dw;
#pragma unroll
  for (int mk = 32; mk; mk >>= 1) s += __shfl_xor(s, mk, 64);
  if (lane == 0) rowsum[row] = s;
}

// ---------- deterministic final loss reduce ----------
__global__ void loss_k(const float* __restrict__ rowsum, float* __restrict__ out) {
  __shared__ float sm[4];
  const int t = threadIdx.x;
  float s = 0.f;
  for (int j = t; j < N_ROWS; j += 256) s += rowsum[j];
#pragma unroll
  for (int mk = 32; mk; mk >>= 1) s += __shfl_xor(s, mk, 64);
  if ((t & 63) == 0) sm[t >> 6] = s;
  __syncthreads();
  if (t == 0) out[0] = 2.0f * (sm[0] + sm[1] + sm[2] + sm[3]) / (float)(N_ROWS * DDIM);
}

extern "C" void kernel_launch(void* const* d_in, const int* in_sizes, int n_in,
                              void* d_out, int out_size, void* d_ws, size_t ws_size,
                              hipStream_t stream) {
  const float* x   = (const float*)d_in[0];          // [16,1024,256] f32
  const float* emb = (const float*)d_in[1];          // [256,8192] f32
  float* qout = (float*)d_out;                       // 4,194,304 q_st + 1 loss

  char* w = (char*)d_ws;
  unsigned long long* keys = (unsigned long long*)w;                 // 128 KB
  float* rowsum = (float*)(w + 131072);                              // 64 KB
  __bf16* xhi = (__bf16*)(w + 196608);                               // 8 MB
  __bf16* xlo = xhi + (size_t)N_ROWS * DDIM;                         // 8 MB
  __bf16* ehi = xlo + (size_t)N_ROWS * DDIM;                         // 4 MB
  __bf16* elo = ehi + (size_t)N_CODES * DDIM;                        // 4 MB
  float*  embT = (float*)(elo + (size_t)N_CODES * DDIM);             // 8 MB
  float*  enorm = embT + (size_t)N_CODES * DDIM;                     // 32 KB

  hipFuncSetAttribute((const void*)vq_main_k,
                      hipFuncAttributeMaxDynamicSharedMemorySize, 3 * BUFB);

  hipMemsetAsync(keys, 0, N_ROWS * sizeof(unsigned long long), stream);  // atomicMax
  prep_x_k<<<4096, 256, 0, stream>>>(x, xhi, xlo);
  prep_e_k<<<dim3(N_CODES / 64, DDIM / 64), 256, 0, stream>>>(emb, ehi, elo, embT);
  enorm_k<<<N_CODES / 256, 256, 0, stream>>>(emb, enorm);
  vq_main_k<<<2048, 512, 3 * BUFB, stream>>>(xhi, xlo, ehi, elo, enorm, keys);
  gather_k<<<N_ROWS, 64, 0, stream>>>(x, embT, keys, qout, rowsum);
  loss_k<<<1, 256, 0, stream>>>(rowsum, qout + (size_t)N_ROWS * DDIM);
}